// Round 2
// baseline (356.505 us; speedup 1.0000x reference)
//
#include <hip/hip_runtime.h>

// Interpolate1D: stride-2 linear upsample along axis 1.
//   x:   (B=16, N=8192, C=256) fp32  (128 MiB)
//   out: (B=16, 2N=16384, C=256) fp32 (256 MiB)
//   out[:,2k,:]   = x[:,k,:]
//   out[:,2k+1,:] = 0.5*(x[:,k,:] + x[:,k+1,:])   (k<N-1)
//   out[:,2N-1,:] = x[:,N-1,:]
//
// Traffic floor: 134 MB read + 268 MB write = 402 MB -> ~64 us @ 6.3 TB/s.
//
// R2 change: deep per-thread streams. Each thread owns KPT=8 consecutive
// input rows at one channel lane (c4). The neighbor row of iteration j is
// the main row of iteration j+1, carried in a register -> 9 row-loads per
// 8 outputs (was 16), and #pragma unroll exposes 8 independent loads for
// software pipelining (deep MLP per wave). Tests the hypothesis that the
// old 1-item-per-thread version (8.4M short-lived threads, 2 loads in
// flight each) was issue/MLP-limited rather than HBM-limited.
// Addressing stays perfectly coalesced: lane==c4, so each wave iteration
// is a 1 KiB contiguous load + a 2 KiB contiguous store pair; a wave's
// 8 iterations cover a 32 KiB contiguous output span.

#define C4    64      // 256 floats / 4
#define NROW  8192
#define BATCH 16
#define KPT   8       // input rows per thread

typedef float vfloat4 __attribute__((ext_vector_type(4)));

__global__ __launch_bounds__(256) void Interpolate1D_kernel(
    const vfloat4* __restrict__ x, vfloat4* __restrict__ out) {
    unsigned int tid = blockIdx.x * blockDim.x + threadIdx.x; // 0..1048575
    unsigned int c4 = tid & (C4 - 1);   // channel lane 0..63
    unsigned int rb = tid >> 6;         // row-block 0..16383
    unsigned int g0 = rb * KPT;         // first global row (b*NROW + k)

    size_t in_i = (size_t)g0 * C4 + c4;        // float4 index of row g0, lane c4
    size_t o    = ((size_t)in_i << 1) - c4;    // float4 index of out row 2*g0

    vfloat4 a = x[in_i];

    #pragma unroll
    for (int j = 0; j < KPT; ++j) {
        unsigned int g = g0 + j;
        bool last = ((g & (NROW - 1)) == (NROW - 1));  // last row of its batch
        vfloat4 nb = last ? a : x[in_i + C4];
        vfloat4 mid = 0.5f * (a + nb);
        out[o]      = a;
        out[o + C4] = mid;
        a = nb;
        in_i += C4;
        o += 2 * C4;
    }
}

extern "C" void kernel_launch(void* const* d_in, const int* in_sizes, int n_in,
                              void* d_out, int out_size, void* d_ws, size_t ws_size,
                              hipStream_t stream) {
    const vfloat4* x = (const vfloat4*)d_in[0];
    vfloat4* out = (vfloat4*)d_out;

    const unsigned int total4  = BATCH * NROW * C4;       // 8,388,608 float4
    const unsigned int threads = total4 / KPT;            // 1,048,576
    const unsigned int block   = 256;
    const unsigned int grid    = threads / block;         // 4096
    Interpolate1D_kernel<<<grid, block, 0, stream>>>(x, out);
}